// Round 6
// baseline (603.652 us; speedup 1.0000x reference)
//
#include <hip/hip_runtime.h>
#include <hip/hip_bf16.h>

// ---------------------------------------------------------------------------
// GAT 2-layer model on MI355X — round 6.
// GEMMs are LDS-free: operands pre-swizzled into MFMA-fragment-tiled layout
// (1 KB chunk = one 16x32 bf16 fragment; lane L owns bytes L*16..+16).
// K-loop: fully unrolled, register double-buffered, coalesced dwordx4 loads
// direct to registers + MFMA, no barriers -> compiler emits fine-grained
// vmcnt pipeline with imm-offset addressing (R5 post-mortem: runtime-k
// indexing cost ~6 VALU/load and saturated the VALU pipe at 58% busy).
// Layer1 commuted: z = softmax-agg of x rows (attn1 writes z_sw directly)
//                  h2 = ELU(z_h @ W1_h + b1)  (epilogue LDS-transposes tile
//                  to write h2b_sw fragment-tiled)
// Layer2: y = h2@W2 split-K=4 -> fused reduce+alpha -> attn2+b2.
// ---------------------------------------------------------------------------

#define N_NODES 8192
#define N_EDGES 32768
#define E_TOT   (N_EDGES + N_NODES)   // self-loops appended
#define D_IN    768
#define H1      8
#define HC1     (H1 * D_IN)           // 6144
#define KSPLIT  4
#define KSLICE  (HC1 / KSPLIT)        // 1536

typedef unsigned short ushort_t;
using short8  = __attribute__((ext_vector_type(8))) short;
using floatx4 = __attribute__((ext_vector_type(4))) float;

__device__ __forceinline__ float bf2f(unsigned short u) {
  return __uint_as_float(((unsigned)u) << 16);
}
__device__ __forceinline__ unsigned short f2bf(float f) {
  unsigned u = __float_as_uint(f);
  unsigned r = (u + 0x7fffu + ((u >> 16) & 1u)) >> 16;  // RNE
  return (unsigned short)r;
}

// ---------------------------------------------------------------------------
// frag_transpose: W[Kdim][Ndim] fp32 row-major -> sw-layout of Bt[N][K] bf16.
// ---------------------------------------------------------------------------
__global__ __launch_bounds__(64) void frag_transpose_kernel(
    const float* __restrict__ W, ushort_t* __restrict__ out,
    int Kdim, int Ndim) {
  const int bn = blockIdx.x;
  const int bk = blockIdx.y;
  const int lane = threadIdx.x;
  const int lrow = lane & 15, lq = lane >> 4;
  const int n = bn * 16 + lrow;
  const int kb = bk * 32 + lq * 8;
  ushort_t v[8];
#pragma unroll
  for (int e = 0; e < 8; ++e)
    v[e] = f2bf(W[(size_t)(kb + e) * Ndim + n]);
  *(short8*)(out + ((size_t)bn * (Kdim >> 5) + bk) * 512 + lane * 8) =
      *(short8*)v;
}

// ---------------------------------------------------------------------------
// awS[d][h] = sum_c W1[d][h*768+c]*a_src1[h*768+c]; awD likewise.
// ---------------------------------------------------------------------------
__global__ void prep_aw_kernel(const float* __restrict__ W1,
                               const float* __restrict__ aS,
                               const float* __restrict__ aD,
                               float* __restrict__ awS,
                               float* __restrict__ awD) {
  const int d = blockIdx.x;
  const int t = threadIdx.x;
  const float* row = W1 + (size_t)d * HC1;
  float ps[H1], pd[H1];
#pragma unroll
  for (int h = 0; h < H1; ++h) { ps[h] = 0.f; pd[h] = 0.f; }
#pragma unroll
  for (int h = 0; h < H1; ++h)
#pragma unroll
    for (int j = 0; j < 3; ++j) {
      int idx = h * 768 + j * 256 + t;
      float w = row[idx];
      ps[h] += w * aS[idx];
      pd[h] += w * aD[idx];
    }
#pragma unroll
  for (int h = 0; h < H1; ++h)
    for (int off = 32; off > 0; off >>= 1) {
      ps[h] += __shfl_down(ps[h], off, 64);
      pd[h] += __shfl_down(pd[h], off, 64);
    }
  __shared__ float red[2][4][H1];
  int w = t >> 6;
  if ((t & 63) == 0) {
#pragma unroll
    for (int h = 0; h < H1; ++h) { red[0][w][h] = ps[h]; red[1][w][h] = pd[h]; }
  }
  __syncthreads();
  if (t < H1)
    awS[d * H1 + t] = red[0][0][t] + red[0][1][t] + red[0][2][t] + red[0][3][t];
  else if (t >= 64 && t < 64 + H1) {
    int h = t - 64;
    awD[d * H1 + h] = red[1][0][h] + red[1][1][h] + red[1][2][h] + red[1][3][h];
  }
}

// ---------------------------------------------------------------------------
// per node: xb = bf16(x); as1[n,h] = x[n,:]@awS[:,h]; ad1 likewise.
// ---------------------------------------------------------------------------
__global__ void node_prep_kernel(const float* __restrict__ x,
                                 const float* __restrict__ awS,
                                 const float* __restrict__ awD,
                                 ushort_t* __restrict__ xb,
                                 float* __restrict__ as1,
                                 float* __restrict__ ad1) {
  const int n = blockIdx.x;
  const int t = threadIdx.x;
  float ps[H1], pd[H1];
#pragma unroll
  for (int h = 0; h < H1; ++h) { ps[h] = 0.f; pd[h] = 0.f; }
#pragma unroll
  for (int j = 0; j < 3; ++j) {
    int d = j * 256 + t;
    float xv = x[(size_t)n * 768 + d];
    xb[(size_t)n * 768 + d] = f2bf(xv);
    const float4* s4 = (const float4*)(awS + d * 8);
    const float4* d4 = (const float4*)(awD + d * 8);
    float4 a0 = s4[0], a1 = s4[1];
    float4 c0 = d4[0], c1 = d4[1];
    ps[0] += xv * a0.x; ps[1] += xv * a0.y; ps[2] += xv * a0.z; ps[3] += xv * a0.w;
    ps[4] += xv * a1.x; ps[5] += xv * a1.y; ps[6] += xv * a1.z; ps[7] += xv * a1.w;
    pd[0] += xv * c0.x; pd[1] += xv * c0.y; pd[2] += xv * c0.z; pd[3] += xv * c0.w;
    pd[4] += xv * c1.x; pd[5] += xv * c1.y; pd[6] += xv * c1.z; pd[7] += xv * c1.w;
  }
#pragma unroll
  for (int h = 0; h < H1; ++h)
    for (int off = 32; off > 0; off >>= 1) {
      ps[h] += __shfl_down(ps[h], off, 64);
      pd[h] += __shfl_down(pd[h], off, 64);
    }
  __shared__ float red[2][4][H1];
  int w = t >> 6;
  if ((t & 63) == 0) {
#pragma unroll
    for (int h = 0; h < H1; ++h) { red[0][w][h] = ps[h]; red[1][w][h] = pd[h]; }
  }
  __syncthreads();
  if (t < H1)
    as1[n * H1 + t] = red[0][0][t] + red[0][1][t] + red[0][2][t] + red[0][3][t];
  else if (t >= 64 && t < 64 + H1) {
    int h = t - 64;
    ad1[n * H1 + h] = red[1][0][h] + red[1][1][h] + red[1][2][h] + red[1][3][h];
  }
}

// ---------------------------------------------------------------------------
// CSR build: deg -> exclusive scan -> fill
// ---------------------------------------------------------------------------
__global__ void deg_kernel(const int* __restrict__ dst, int* __restrict__ deg) {
  int e = blockIdx.x * blockDim.x + threadIdx.x;
  if (e >= E_TOT) return;
  int d = (e < N_EDGES) ? dst[e] : (e - N_EDGES);
  atomicAdd(&deg[d], 1);
}

__global__ void scan_kernel(const int* __restrict__ deg, int* __restrict__ start,
                            int* __restrict__ cursor) {
  __shared__ int sums[1024];
  int t = threadIdx.x;
  int base = t * 8;
  int local[8];
  int s = 0;
#pragma unroll
  for (int i = 0; i < 8; ++i) { local[i] = s; s += deg[base + i]; }
  sums[t] = s;
  __syncthreads();
  for (int off = 1; off < 1024; off <<= 1) {
    int v = (t >= off) ? sums[t - off] : 0;
    __syncthreads();
    sums[t] += v;
    __syncthreads();
  }
  int excl = (t == 0) ? 0 : sums[t - 1];
#pragma unroll
  for (int i = 0; i < 8; ++i) {
    int st = excl + local[i];
    start[base + i] = st;
    cursor[base + i] = st;
  }
}

__global__ void fill_kernel(const int* __restrict__ dst, int* __restrict__ cursor,
                            int* __restrict__ csr) {
  int e = blockIdx.x * blockDim.x + threadIdx.x;
  if (e >= E_TOT) return;
  int d = (e < N_EDGES) ? dst[e] : (e - N_EDGES);
  int pos = atomicAdd(&cursor[d], 1);
  csr[pos] = e;
}

// ---------------------------------------------------------------------------
// Fused layer-1 attention -> z in sw (fragment-tiled) layout.
// ---------------------------------------------------------------------------
__global__ __launch_bounds__(256) void attn1_kernel(
    const ushort_t* __restrict__ xb, const float* __restrict__ as1,
    const float* __restrict__ ad1, const int* __restrict__ start,
    const int* __restrict__ deg, const int* __restrict__ csr,
    const int* __restrict__ src, ushort_t* __restrict__ z_sw) {
  const int n = blockIdx.x;
  const int t = threadIdx.x;
  const int st = start[n], dg = deg[n];
  const int h = t & 7, eloc = t >> 3;  // 32 edges x 8 heads per chunk
  __shared__ float invd[H1];
  __shared__ float alphaS[32][H1];
  __shared__ int sidx[32];
  __shared__ float red[4][H1];

  // Phase A: denominators (no max-subtraction; logits bounded)
  const float adv = ad1[n * H1 + h];
  float pden = 0.f;
  for (int base = 0; base < dg; base += 32) {
    int ei = base + eloc;
    if (ei < dg) {
      int e = csr[st + ei];
      int s = (e < N_EDGES) ? src[e] : (e - N_EDGES);
      float l = as1[s * H1 + h] + adv;
      l = l > 0.f ? l : 0.2f * l;
      pden += __expf(l);
    }
  }
  pden += __shfl_down(pden, 8, 64);
  pden += __shfl_down(pden, 16, 64);
  pden += __shfl_down(pden, 32, 64);
  if ((t & 63) < 8) red[t >> 6][h] = pden;
  __syncthreads();
  if (t < 8) invd[t] = 1.0f / (red[0][t] + red[1][t] + red[2][t] + red[3][t]);
  __syncthreads();

  // per-pass ownership
  int hp[3], ip[3];
#pragma unroll
  for (int p = 0; p < 3; ++p) {
    int c8 = p * 256 + t;
    hp[p] = c8 / 96;          // head
    ip[p] = c8 % 96;          // uint4 index within xb row
  }
  float acc[3][8];
#pragma unroll
  for (int p = 0; p < 3; ++p)
#pragma unroll
    for (int e = 0; e < 8; ++e) acc[p][e] = 0.f;

  for (int base = 0; base < dg; base += 32) {
    int cnt = dg - base; if (cnt > 32) cnt = 32;
    if (eloc < cnt) {
      int e = csr[st + base + eloc];
      int s = (e < N_EDGES) ? src[e] : (e - N_EDGES);
      float l = as1[s * H1 + h] + adv;
      l = l > 0.f ? l : 0.2f * l;
      alphaS[eloc][h] = __expf(l) * invd[h];
      if (h == 0) sidx[eloc] = s;
    }
    __syncthreads();
    for (int ei = 0; ei < cnt; ++ei) {
      int s = sidx[ei];
      const uint4* xrow = (const uint4*)(xb + (size_t)s * 768);
#pragma unroll
      for (int p = 0; p < 3; ++p) {
        uint4 v = xrow[ip[p]];
        float al = alphaS[ei][hp[p]];
        unsigned uu[4] = {v.x, v.y, v.z, v.w};
#pragma unroll
        for (int q = 0; q < 4; ++q) {
          acc[p][2 * q]     += al * __uint_as_float(uu[q] << 16);
          acc[p][2 * q + 1] += al * __uint_as_float(uu[q] & 0xffff0000u);
        }
      }
    }
    __syncthreads();
  }
  // write sw layout: k = (p*256+t)*8
#pragma unroll
  for (int p = 0; p < 3; ++p) {
    int c8 = p * 256 + t;
    int k = c8 * 8;
    size_t chunk = (size_t)(n >> 4) * 192 + (k >> 5);
    int word = ((k >> 3) & 3) * 16 + (n & 15);
    ushort_t v[8];
#pragma unroll
    for (int e = 0; e < 8; ++e) v[e] = f2bf(acc[p][e]);
    *(short8*)(z_sw + chunk * 512 + word * 8) = *(short8*)v;
  }
}

// ---------------------------------------------------------------------------
// LDS-free MFMA helpers. K-loop fully unrolled (compile-time chunk offsets ->
// imm-offset addressing, minimal VALU), register double-buffer, no barriers.
// ---------------------------------------------------------------------------
#define LOAD4(dst, base_sw, ch, k32)                                           \
  _Pragma("unroll") for (int q = 0; q < 4; ++q)                                \
      dst[q] = *((const short8*)(base_sw) + ((size_t)(ch[q] + (k32))) * 64 + lane);

#define MFMA16(af, bf)                                                         \
  _Pragma("unroll") for (int i_ = 0; i_ < 4; ++i_)                             \
      _Pragma("unroll") for (int j_ = 0; j_ < 4; ++j_)                         \
          acc[i_][j_] = __builtin_amdgcn_mfma_f32_16x16x32_bf16(               \
              af[i_], bf[j_], acc[i_][j_], 0, 0, 0);

#define GEMM_KLOOP(NCH, Asw, Bsw)                                              \
  {                                                                            \
    short8 abuf[2][4], bbuf[2][4];                                             \
    LOAD4(abuf[0], Asw, chA, 0)                                                \
    LOAD4(bbuf[0], Bsw, chB, 0)                                                \
    _Pragma("unroll") for (int k = 0; k < (NCH); ++k) {                        \
      const int cur = k & 1, nxt = cur ^ 1;                                    \
      if (k + 1 < (NCH)) {                                                     \
        LOAD4(abuf[nxt], Asw, chA, k + 1)                                      \
        LOAD4(bbuf[nxt], Bsw, chB, k + 1)                                      \
      }                                                                        \
      MFMA16(abuf[cur], bbuf[cur])                                             \
    }                                                                          \
  }

// ---------------------------------------------------------------------------
// Layer-1 GEMM (per-head, 128x128 tile, LDS-free): h2 = ELU(z_h@W1_h^T + b1).
// Grid 3072: head = id&7 (pins head per XCD), j=id>>3: n_t=j%6, m_t=j/6.
// Epilogue: LDS-transpose the C tile and store h2b in sw layout (K=6144).
// ---------------------------------------------------------------------------
__global__ __launch_bounds__(256) void gemm_l1_kernel(
    const ushort_t* __restrict__ Asw, const ushort_t* __restrict__ Bsw,
    const float* __restrict__ biasb, ushort_t* __restrict__ Csw) {
  __shared__ ushort_t tile[128 * 136];
  const int id = blockIdx.x;
  const int head = id & 7;
  const int j_id = id >> 3;
  const int n_t = j_id % 6;
  const int m_t = j_id / 6;
  const int tid = threadIdx.x;
  const int lane = tid & 63;
  const int w = tid >> 6;
  const int wm = w >> 1, wn = w & 1;
  const int lrow = lane & 15, lq = lane >> 4;

  int chA[4], chB[4];
#pragma unroll
  for (int q = 0; q < 4; ++q) {
    chA[q] = (m_t * 8 + wm * 4 + q) * 192 + head * 24;  // z_sw: K=6144
    chB[q] = (head * 48 + n_t * 8 + wn * 4 + q) * 24;   // w1t_sw: K=768
  }
  floatx4 acc[4][4];
#pragma unroll
  for (int i = 0; i < 4; ++i)
#pragma unroll
    for (int j = 0; j < 4; ++j) acc[i][j] = {0.f, 0.f, 0.f, 0.f};

  GEMM_KLOOP(24, Asw, Bsw)

  // epilogue: bias+ELU -> LDS tile -> fragment-tiled global write
  const float* bias = biasb + head * 768 + n_t * 128;
#pragma unroll
  for (int i = 0; i < 4; ++i) {
    int row_l = wm * 64 + i * 16 + lq * 4;
#pragma unroll
    for (int j = 0; j < 4; ++j) {
      int col_l = wn * 64 + j * 16 + lrow;
      float bv = bias[col_l];
#pragma unroll
      for (int r = 0; r < 4; ++r) {
        float v = acc[i][j][r] + bv;
        v = v > 0.f ? v : expm1f(v);  // ELU
        tile[(row_l + r) * 136 + col_l] = f2bf(v);
      }
    }
  }
  __syncthreads();
#pragma unroll
  for (int cc = 0; cc < 8; ++cc) {
    int ch = w * 8 + cc;          // 32 chunks in the 128x128 tile
    int RB = ch >> 2, kg = ch & 3;
    short8 vv = *(const short8*)&tile[(RB * 16 + lrow) * 136 + kg * 32 + lq * 8];
    size_t chunk_g = (size_t)(m_t * 8 + RB) * 192 + head * 24 + n_t * 4 + kg;
    *((short8*)Csw + chunk_g * 64 + lane) = vv;
  }
}

// ---------------------------------------------------------------------------
// Layer-2 GEMM split-K=4 (128x128 tile, LDS-free): partials fp32 row-major.
// Grid 1536: c=id&7: s=c>>1 (K-slice per XCD-pair), m_t=(j/6)*2+(c&1), n_t=j%6.
// ---------------------------------------------------------------------------
__global__ __launch_bounds__(256) void gemm_l2_kernel(
    const ushort_t* __restrict__ Asw, const ushort_t* __restrict__ Bsw,
    float* __restrict__ Cp) {
  const int id = blockIdx.x;
  const int c = id & 7;
  const int s = c >> 1;
  const int j_id = id >> 3;
  const int n_t = j_id % 6;
  const int m_t = (j_id / 6) * 2 + (c & 1);
  const int tid = threadIdx.x;
  const int lane = tid & 63;
  const int w = tid >> 6;
  const int wm = w >> 1, wn = w & 1;
  const int lrow = lane & 15, lq = lane >> 4;

  int chA[4], chB[4];
#pragma unroll
  for (int q = 0; q < 4; ++q) {
    chA[q] = (m_t * 8 + wm * 4 + q) * 192 + s * 48;  // h2b_sw: K=6144
    chB[q] = (n_t * 8 + wn * 4 + q) * 192 + s * 48;  // w2t_sw: K=6144
  }
  floatx4 acc[4][4];
#pragma unroll
  for (int i = 0; i < 4; ++i)
#pragma unroll
    for (int j = 0; j < 4; ++j) acc[i][j] = {0.f, 0.f, 0.f, 0.f};

  GEMM_KLOOP(48, Asw, Bsw)

  float* C = Cp + (size_t)s * N_NODES * 768;
  const int m0 = m_t * 128, n0 = n_t * 128;
#pragma unroll
  for (int i = 0; i < 4; ++i) {
    int row_b = m0 + wm * 64 + i * 16 + lq * 4;
#pragma unroll
    for (int j = 0; j < 4; ++j) {
      int col = n0 + wn * 64 + j * 16 + lrow;
#pragma unroll
      for (int r = 0; r < 4; ++r)
        C[(size_t)(row_b + r) * 768 + col] = acc[i][j][r];
    }
  }
}

// ---------------------------------------------------------------------------
// Fused: yb = bf16(sum of 4 partials); as2/ad2 = y . a_src2/a_dst2 per node.
// ---------------------------------------------------------------------------
__global__ void reduce_alpha2_kernel(const float* __restrict__ parts,
                                     const float* __restrict__ aS,
                                     const float* __restrict__ aD,
                                     ushort_t* __restrict__ yb,
                                     float* __restrict__ as2,
                                     float* __restrict__ ad2) {
  const int n = blockIdx.x;
  const int t = threadIdx.x;
  const size_t S = (size_t)N_NODES * 768;
  float ps = 0.f, pd = 0.f;
#pragma unroll
  for (int j = 0; j < 3; ++j) {
    int cidx = j * 256 + t;
    size_t base = (size_t)n * 768 + cidx;
    float v = parts[base] + parts[base + S] + parts[base + 2 * S] +
              parts[base + 3 * S];
    yb[base] = f2bf(v);
    ps += v * aS[cidx];
    pd += v * aD[cidx];
  }
  for (int off = 32; off > 0; off >>= 1) {
    ps += __shfl_down(ps, off, 64);
    pd += __shfl_down(pd, off, 64);
  }
  __shared__ float red[2][4];
  int w = t >> 6;
  if ((t & 63) == 0) { red[0][w] = ps; red[1][w] = pd; }
  __syncthreads();
  if (t == 0) as2[n] = red[0][0] + red[0][1] + red[0][2] + red[0][3];
  if (t == 64) ad2[n] = red[1][0] + red[1][1] + red[1][2] + red[1][3];
}

// ---------------------------------------------------------------------------
// Fused layer-2 attention (H=1) + bias: out[n,c] = sum alpha*y[src,c] + b2.
// ---------------------------------------------------------------------------
__global__ __launch_bounds__(256) void attn2_kernel(
    const ushort_t* __restrict__ yb, const float* __restrict__ as2,
    const float* __restrict__ ad2, const int* __restrict__ start,
    const int* __restrict__ deg, const int* __restrict__ csr,
    const int* __restrict__ src, const float* __restrict__ b2,
    float* __restrict__ out) {
  const int n = blockIdx.x;
  const int t = threadIdx.x;
  const int st = start[n], dg = deg[n];
  __shared__ float alphaS[64];
  __shared__ int sidx[64];
  __shared__ float red[4];
  __shared__ float invd_sh;

  const float adv = ad2[n];
  float pden = 0.f;
  for (int ei = t; ei < dg; ei += 256) {
    int e = csr[st + ei];
    int s = (e < N_EDGES) ? src[e] : (e - N_EDGES);
    float l = as2[s] + adv;
    l = l > 0.f ? l : 0.2f * l;
    pden += __expf(l);
  }
  for (int off = 32; off > 0; off >>= 1) pden += __shfl_down(pden, off, 64);
  if ((t & 63) == 0) red[t >> 6] = pden;
  __syncthreads();
  if (t == 0) invd_sh = 1.0f / (red[0] + red[1] + red[2] + red[3]);
  __syncthreads();
  const float invd = invd_sh;

  float a0 = 0.f, a1 = 0.f, a2 = 0.f;
  for (int base = 0; base < dg; base += 64) {
    int cnt = dg - base; if (cnt > 64) cnt = 64;
    if (t < cnt) {
      int e = csr[st + base + t];
      int s = (e < N_EDGES) ? src[e] : (e - N_EDGES);
      float l = as2[s] + adv;
      l = l > 0.f ? l : 0.2f * l;
      alphaS[t] = __expf(l) * invd;
      sidx[t] = s;
    }
    __syncthreads();
    for (int ei = 0; ei < cnt; ++ei) {
      float al = alphaS[ei];
      const ushort_t* row = yb + (size_t)sidx[ei] * 768;
      a0 += al * bf2f(row[t]);
      a1 += al * bf2f(row[t + 256]);
      a2 += al * bf2f(row[t + 512]);
    }
    __syncthreads();
  }
  out[(size_t)n * 768 + t]       = a0 + b2[t];
  out[(size_t)n * 768 + t + 256] = a1 + b2[t + 256];
  out[(size_t)n * 768 + t + 512] = a2 + b2[t + 512];
}

// ---------------------------------------------------------------------------
extern "C" void kernel_launch(void* const* d_in, const int* in_sizes, int n_in,
                              void* d_out, int out_size, void* d_ws, size_t ws_size,
                              hipStream_t stream) {
  const float* x      = (const float*)d_in[0];
  const int*   ei     = (const int*)d_in[1];
  const float* W1     = (const float*)d_in[2];
  const float* a_src1 = (const float*)d_in[3];
  const float* a_dst1 = (const float*)d_in[4];
  const float* b1     = (const float*)d_in[5];
  const float* W2     = (const float*)d_in[6];
  const float* a_src2 = (const float*)d_in[7];
  const float* a_dst2 = (const float*)d_in[8];
  const float* b2     = (const float*)d_in[9];
  float* out = (float*)d_out;
  const int* src = ei;
  const int* dst = ei + N_EDGES;

  char* ws = (char*)d_ws;
  size_t off = 0;
  auto alloc = [&](size_t bytes) -> void* {
    void* p = ws + off;
    off = (off + bytes + 255) & ~(size_t)255;
    return p;
  };

  int* deg = (int*)alloc(N_NODES * 4);  // needs zero-init
  float* awS = (float*)alloc(768 * H1 * 4);
  float* awD = (float*)alloc(768 * H1 * 4);
  float* as1 = (float*)alloc(N_NODES * H1 * 4);
  float* ad1 = (float*)alloc(N_NODES * H1 * 4);
  float* as2 = (float*)alloc(N_NODES * 4);
  float* ad2 = (float*)alloc(N_NODES * 4);
  int* start  = (int*)alloc(N_NODES * 4);
  int* cursor = (int*)alloc(N_NODES * 4);
  int* csr    = (int*)alloc(E_TOT * 4);
  ushort_t* xb     = (ushort_t*)alloc((size_t)N_NODES * D_IN * 2);  // -> yb
  ushort_t* w1t_sw = (ushort_t*)alloc((size_t)HC1 * D_IN * 2);
  ushort_t* w2t_sw = (ushort_t*)alloc((size_t)HC1 * D_IN * 2);
  ushort_t* z_sw   = (ushort_t*)alloc((size_t)N_NODES * HC1 * 2);  // -> parts
  ushort_t* h2b_sw = (ushort_t*)alloc((size_t)N_NODES * HC1 * 2);
  ushort_t* yb  = xb;            // xb dead after attn1
  float* parts  = (float*)z_sw;  // z dead after gemm_l1 (same byte size)
  (void)ws_size; (void)n_in; (void)in_sizes; (void)out_size;

  hipMemsetAsync(deg, 0, N_NODES * 4, stream);

  // weight prep
  prep_aw_kernel<<<768, 256, 0, stream>>>(W1, a_src1, a_dst1, awS, awD);
  node_prep_kernel<<<N_NODES, 256, 0, stream>>>(x, awS, awD, xb, as1, ad1);
  // w1t_sw = sw(Bt of W1): Bt[6144][768]
  frag_transpose_kernel<<<dim3(HC1 / 16, D_IN / 32), 64, 0, stream>>>(
      W1, w1t_sw, D_IN, HC1);
  // w2t_sw = sw(Bt of W2): Bt[768][6144]
  frag_transpose_kernel<<<dim3(D_IN / 16, HC1 / 32), 64, 0, stream>>>(
      W2, w2t_sw, HC1, D_IN);

  // CSR build (graph identical for both layers)
  deg_kernel<<<(E_TOT + 255) / 256, 256, 0, stream>>>(dst, deg);
  scan_kernel<<<1, 1024, 0, stream>>>(deg, start, cursor);
  fill_kernel<<<(E_TOT + 255) / 256, 256, 0, stream>>>(dst, cursor, csr);

  // layer-1: fused attention -> z_sw, then per-head LDS-free GEMM
  attn1_kernel<<<N_NODES, 256, 0, stream>>>(xb, as1, ad1, start, deg, csr,
                                            src, z_sw);
  gemm_l1_kernel<<<8 * 64 * 6, 256, 0, stream>>>(z_sw, w1t_sw, b1, h2b_sw);

  // layer-2: split-K LDS-free GEMM -> fused reduce+alpha -> attention + bias
  gemm_l2_kernel<<<KSPLIT * 2 * 32 * 6, 256, 0, stream>>>(h2b_sw, w2t_sw,
                                                          parts);
  reduce_alpha2_kernel<<<N_NODES, 256, 0, stream>>>(parts, a_src2, a_dst2, yb,
                                                    as2, ad2);
  attn2_kernel<<<N_NODES, 256, 0, stream>>>(yb, as2, ad2, start, deg, csr,
                                            src, b2, out);
}

// Round 7
// 538.403 us; speedup vs baseline: 1.1212x; 1.1212x over previous
//
#include <hip/hip_runtime.h>
#include <hip/hip_bf16.h>

// ---------------------------------------------------------------------------
// GAT 2-layer model on MI355X — round 7.
// GEMMs are LDS-free: operands pre-swizzled into MFMA-fragment-tiled layout
// (1 KB chunk = one 16x32 bf16 fragment; lane L owns bytes L*16..+16).
// K-loop: R5's rotating double-buffer (prefetch distance ~2.5 MFMA batches,
// covers ~200cyc L2 latency) + pointer-bump addressing (imm offsets 0/1K/2K/3K,
// one +=2KB bump per 2 chunks) -> minimal VALU, R5 schedule preserved.
// R6 post-mortem: full unroll shrank prefetch distance to ~1 batch -> both
// pipes idle (VALU 8%, MFMA 17%); depth matters more than address VALU.
// Layer1 commuted: z = softmax-agg of x rows (attn1 writes z_sw directly)
//                  h2 = ELU(z_h @ W1_h + b1)  (epilogue LDS-transposes tile
//                  to write h2b_sw fragment-tiled)
// Layer2: y = h2@W2 split-K=4 -> fused reduce+alpha -> attn2+b2.
// ---------------------------------------------------------------------------

#define N_NODES 8192
#define N_EDGES 32768
#define E_TOT   (N_EDGES + N_NODES)   // self-loops appended
#define D_IN    768
#define H1      8
#define HC1     (H1 * D_IN)           // 6144
#define KSPLIT  4
#define KSLICE  (HC1 / KSPLIT)        // 1536

typedef unsigned short ushort_t;
using short8  = __attribute__((ext_vector_type(8))) short;
using floatx4 = __attribute__((ext_vector_type(4))) float;

__device__ __forceinline__ float bf2f(unsigned short u) {
  return __uint_as_float(((unsigned)u) << 16);
}
__device__ __forceinline__ unsigned short f2bf(float f) {
  unsigned u = __float_as_uint(f);
  unsigned r = (u + 0x7fffu + ((u >> 16) & 1u)) >> 16;  // RNE
  return (unsigned short)r;
}

// ---------------------------------------------------------------------------
// frag_transpose: W[Kdim][Ndim] fp32 row-major -> sw-layout of Bt[N][K] bf16.
// ---------------------------------------------------------------------------
__global__ __launch_bounds__(64) void frag_transpose_kernel(
    const float* __restrict__ W, ushort_t* __restrict__ out,
    int Kdim, int Ndim) {
  const int bn = blockIdx.x;
  const int bk = blockIdx.y;
  const int lane = threadIdx.x;
  const int lrow = lane & 15, lq = lane >> 4;
  const int n = bn * 16 + lrow;
  const int kb = bk * 32 + lq * 8;
  ushort_t v[8];
#pragma unroll
  for (int e = 0; e < 8; ++e)
    v[e] = f2bf(W[(size_t)(kb + e) * Ndim + n]);
  *(short8*)(out + ((size_t)bn * (Kdim >> 5) + bk) * 512 + lane * 8) =
      *(short8*)v;
}

// ---------------------------------------------------------------------------
// awS[d][h] = sum_c W1[d][h*768+c]*a_src1[h*768+c]; awD likewise.
// ---------------------------------------------------------------------------
__global__ void prep_aw_kernel(const float* __restrict__ W1,
                               const float* __restrict__ aS,
                               const float* __restrict__ aD,
                               float* __restrict__ awS,
                               float* __restrict__ awD) {
  const int d = blockIdx.x;
  const int t = threadIdx.x;
  const float* row = W1 + (size_t)d * HC1;
  float ps[H1], pd[H1];
#pragma unroll
  for (int h = 0; h < H1; ++h) { ps[h] = 0.f; pd[h] = 0.f; }
#pragma unroll
  for (int h = 0; h < H1; ++h)
#pragma unroll
    for (int j = 0; j < 3; ++j) {
      int idx = h * 768 + j * 256 + t;
      float w = row[idx];
      ps[h] += w * aS[idx];
      pd[h] += w * aD[idx];
    }
#pragma unroll
  for (int h = 0; h < H1; ++h)
    for (int off = 32; off > 0; off >>= 1) {
      ps[h] += __shfl_down(ps[h], off, 64);
      pd[h] += __shfl_down(pd[h], off, 64);
    }
  __shared__ float red[2][4][H1];
  int w = t >> 6;
  if ((t & 63) == 0) {
#pragma unroll
    for (int h = 0; h < H1; ++h) { red[0][w][h] = ps[h]; red[1][w][h] = pd[h]; }
  }
  __syncthreads();
  if (t < H1)
    awS[d * H1 + t] = red[0][0][t] + red[0][1][t] + red[0][2][t] + red[0][3][t];
  else if (t >= 64 && t < 64 + H1) {
    int h = t - 64;
    awD[d * H1 + h] = red[1][0][h] + red[1][1][h] + red[1][2][h] + red[1][3][h];
  }
}

// ---------------------------------------------------------------------------
// per node: xb = bf16(x); as1[n,h] = x[n,:]@awS[:,h]; ad1 likewise.
// ---------------------------------------------------------------------------
__global__ void node_prep_kernel(const float* __restrict__ x,
                                 const float* __restrict__ awS,
                                 const float* __restrict__ awD,
                                 ushort_t* __restrict__ xb,
                                 float* __restrict__ as1,
                                 float* __restrict__ ad1) {
  const int n = blockIdx.x;
  const int t = threadIdx.x;
  float ps[H1], pd[H1];
#pragma unroll
  for (int h = 0; h < H1; ++h) { ps[h] = 0.f; pd[h] = 0.f; }
#pragma unroll
  for (int j = 0; j < 3; ++j) {
    int d = j * 256 + t;
    float xv = x[(size_t)n * 768 + d];
    xb[(size_t)n * 768 + d] = f2bf(xv);
    const float4* s4 = (const float4*)(awS + d * 8);
    const float4* d4 = (const float4*)(awD + d * 8);
    float4 a0 = s4[0], a1 = s4[1];
    float4 c0 = d4[0], c1 = d4[1];
    ps[0] += xv * a0.x; ps[1] += xv * a0.y; ps[2] += xv * a0.z; ps[3] += xv * a0.w;
    ps[4] += xv * a1.x; ps[5] += xv * a1.y; ps[6] += xv * a1.z; ps[7] += xv * a1.w;
    pd[0] += xv * c0.x; pd[1] += xv * c0.y; pd[2] += xv * c0.z; pd[3] += xv * c0.w;
    pd[4] += xv * c1.x; pd[5] += xv * c1.y; pd[6] += xv * c1.z; pd[7] += xv * c1.w;
  }
#pragma unroll
  for (int h = 0; h < H1; ++h)
    for (int off = 32; off > 0; off >>= 1) {
      ps[h] += __shfl_down(ps[h], off, 64);
      pd[h] += __shfl_down(pd[h], off, 64);
    }
  __shared__ float red[2][4][H1];
  int w = t >> 6;
  if ((t & 63) == 0) {
#pragma unroll
    for (int h = 0; h < H1; ++h) { red[0][w][h] = ps[h]; red[1][w][h] = pd[h]; }
  }
  __syncthreads();
  if (t < H1)
    as1[n * H1 + t] = red[0][0][t] + red[0][1][t] + red[0][2][t] + red[0][3][t];
  else if (t >= 64 && t < 64 + H1) {
    int h = t - 64;
    ad1[n * H1 + h] = red[1][0][h] + red[1][1][h] + red[1][2][h] + red[1][3][h];
  }
}

// ---------------------------------------------------------------------------
// CSR build: deg -> exclusive scan -> fill
// ---------------------------------------------------------------------------
__global__ void deg_kernel(const int* __restrict__ dst, int* __restrict__ deg) {
  int e = blockIdx.x * blockDim.x + threadIdx.x;
  if (e >= E_TOT) return;
  int d = (e < N_EDGES) ? dst[e] : (e - N_EDGES);
  atomicAdd(&deg[d], 1);
}

__global__ void scan_kernel(const int* __restrict__ deg, int* __restrict__ start,
                            int* __restrict__ cursor) {
  __shared__ int sums[1024];
  int t = threadIdx.x;
  int base = t * 8;
  int local[8];
  int s = 0;
#pragma unroll
  for (int i = 0; i < 8; ++i) { local[i] = s; s += deg[base + i]; }
  sums[t] = s;
  __syncthreads();
  for (int off = 1; off < 1024; off <<= 1) {
    int v = (t >= off) ? sums[t - off] : 0;
    __syncthreads();
    sums[t] += v;
    __syncthreads();
  }
  int excl = (t == 0) ? 0 : sums[t - 1];
#pragma unroll
  for (int i = 0; i < 8; ++i) {
    int st = excl + local[i];
    start[base + i] = st;
    cursor[base + i] = st;
  }
}

__global__ void fill_kernel(const int* __restrict__ dst, int* __restrict__ cursor,
                            int* __restrict__ csr) {
  int e = blockIdx.x * blockDim.x + threadIdx.x;
  if (e >= E_TOT) return;
  int d = (e < N_EDGES) ? dst[e] : (e - N_EDGES);
  int pos = atomicAdd(&cursor[d], 1);
  csr[pos] = e;
}

// ---------------------------------------------------------------------------
// Fused layer-1 attention -> z in sw (fragment-tiled) layout.
// ---------------------------------------------------------------------------
__global__ __launch_bounds__(256) void attn1_kernel(
    const ushort_t* __restrict__ xb, const float* __restrict__ as1,
    const float* __restrict__ ad1, const int* __restrict__ start,
    const int* __restrict__ deg, const int* __restrict__ csr,
    const int* __restrict__ src, ushort_t* __restrict__ z_sw) {
  const int n = blockIdx.x;
  const int t = threadIdx.x;
  const int st = start[n], dg = deg[n];
  const int h = t & 7, eloc = t >> 3;  // 32 edges x 8 heads per chunk
  __shared__ float invd[H1];
  __shared__ float alphaS[32][H1];
  __shared__ int sidx[32];
  __shared__ float red[4][H1];

  // Phase A: denominators (no max-subtraction; logits bounded)
  const float adv = ad1[n * H1 + h];
  float pden = 0.f;
  for (int base = 0; base < dg; base += 32) {
    int ei = base + eloc;
    if (ei < dg) {
      int e = csr[st + ei];
      int s = (e < N_EDGES) ? src[e] : (e - N_EDGES);
      float l = as1[s * H1 + h] + adv;
      l = l > 0.f ? l : 0.2f * l;
      pden += __expf(l);
    }
  }
  pden += __shfl_down(pden, 8, 64);
  pden += __shfl_down(pden, 16, 64);
  pden += __shfl_down(pden, 32, 64);
  if ((t & 63) < 8) red[t >> 6][h] = pden;
  __syncthreads();
  if (t < 8) invd[t] = 1.0f / (red[0][t] + red[1][t] + red[2][t] + red[3][t]);
  __syncthreads();

  // per-pass ownership
  int hp[3], ip[3];
#pragma unroll
  for (int p = 0; p < 3; ++p) {
    int c8 = p * 256 + t;
    hp[p] = c8 / 96;          // head
    ip[p] = c8 % 96;          // uint4 index within xb row
  }
  float acc[3][8];
#pragma unroll
  for (int p = 0; p < 3; ++p)
#pragma unroll
    for (int e = 0; e < 8; ++e) acc[p][e] = 0.f;

  for (int base = 0; base < dg; base += 32) {
    int cnt = dg - base; if (cnt > 32) cnt = 32;
    if (eloc < cnt) {
      int e = csr[st + base + eloc];
      int s = (e < N_EDGES) ? src[e] : (e - N_EDGES);
      float l = as1[s * H1 + h] + adv;
      l = l > 0.f ? l : 0.2f * l;
      alphaS[eloc][h] = __expf(l) * invd[h];
      if (h == 0) sidx[eloc] = s;
    }
    __syncthreads();
    for (int ei = 0; ei < cnt; ++ei) {
      int s = sidx[ei];
      const uint4* xrow = (const uint4*)(xb + (size_t)s * 768);
#pragma unroll
      for (int p = 0; p < 3; ++p) {
        uint4 v = xrow[ip[p]];
        float al = alphaS[ei][hp[p]];
        unsigned uu[4] = {v.x, v.y, v.z, v.w};
#pragma unroll
        for (int q = 0; q < 4; ++q) {
          acc[p][2 * q]     += al * __uint_as_float(uu[q] << 16);
          acc[p][2 * q + 1] += al * __uint_as_float(uu[q] & 0xffff0000u);
        }
      }
    }
    __syncthreads();
  }
  // write sw layout: k = (p*256+t)*8
#pragma unroll
  for (int p = 0; p < 3; ++p) {
    int c8 = p * 256 + t;
    int k = c8 * 8;
    size_t chunk = (size_t)(n >> 4) * 192 + (k >> 5);
    int word = ((k >> 3) & 3) * 16 + (n & 15);
    ushort_t v[8];
#pragma unroll
    for (int e = 0; e < 8; ++e) v[e] = f2bf(acc[p][e]);
    *(short8*)(z_sw + chunk * 512 + word * 8) = *(short8*)v;
  }
}

// ---------------------------------------------------------------------------
// LDS-free MFMA helpers: rotating double-buffer (R5 depth) with pointer-bump
// addressing. Loads use imm displacements [0]/[64]/[128]/[192] (1-3 KB) and
// one +=128-slot (2 KB) bump per 2-chunk iteration. Tail over-reads <=2
// chunks past each stream (workspace padded).
// ---------------------------------------------------------------------------
#define GEMM_PTRS(Asw, Bsw)                                                    \
  const short8* pa[4];                                                         \
  const short8* pb[4];                                                         \
  _Pragma("unroll") for (int q = 0; q < 4; ++q) {                              \
    pa[q] = (const short8*)(Asw) + (size_t)chA[q] * 64 + lane;                 \
    pb[q] = (const short8*)(Bsw) + (size_t)chB[q] * 64 + lane;                 \
  }

#define LOADP(dst, P, DISP)                                                    \
  _Pragma("unroll") for (int q = 0; q < 4; ++q) dst[q] = P[q][(DISP)];

#define MFMA16(af, bf)                                                         \
  _Pragma("unroll") for (int i_ = 0; i_ < 4; ++i_)                             \
      _Pragma("unroll") for (int j_ = 0; j_ < 4; ++j_)                         \
          acc[i_][j_] = __builtin_amdgcn_mfma_f32_16x16x32_bf16(               \
              af[i_], bf[j_], acc[i_][j_], 0, 0, 0);

#define GEMM_KLOOP(NCH)                                                        \
  {                                                                            \
    short8 a0[4], b0[4], a1[4], b1[4];                                         \
    LOADP(a0, pa, 0) LOADP(b0, pb, 0)                                          \
    LOADP(a1, pa, 64) LOADP(b1, pb, 64)                                        \
    for (int k = 0; k < (NCH); k += 2) {                                       \
      MFMA16(a0, b0)                                                           \
      LOADP(a0, pa, 128) LOADP(b0, pb, 128)                                    \
      MFMA16(a1, b1)                                                           \
      LOADP(a1, pa, 192) LOADP(b1, pb, 192)                                    \
      _Pragma("unroll") for (int q = 0; q < 4; ++q) {                          \
        pa[q] += 128; pb[q] += 128;                                            \
      }                                                                        \
    }                                                                          \
  }

// ---------------------------------------------------------------------------
// Layer-1 GEMM (per-head, 128x128 tile, LDS-free): h2 = ELU(z_h@W1_h^T + b1).
// Grid 3072: head = id&7 (pins head per XCD), j=id>>3: n_t=j%6, m_t=j/6.
// Epilogue: LDS-transpose the C tile and store h2b in sw layout (K=6144).
// ---------------------------------------------------------------------------
__global__ __launch_bounds__(256) void gemm_l1_kernel(
    const ushort_t* __restrict__ Asw, const ushort_t* __restrict__ Bsw,
    const float* __restrict__ biasb, ushort_t* __restrict__ Csw) {
  __shared__ ushort_t tile[128 * 136];
  const int id = blockIdx.x;
  const int head = id & 7;
  const int j_id = id >> 3;
  const int n_t = j_id % 6;
  const int m_t = j_id / 6;
  const int tid = threadIdx.x;
  const int lane = tid & 63;
  const int w = tid >> 6;
  const int wm = w >> 1, wn = w & 1;
  const int lrow = lane & 15, lq = lane >> 4;

  int chA[4], chB[4];
#pragma unroll
  for (int q = 0; q < 4; ++q) {
    chA[q] = (m_t * 8 + wm * 4 + q) * 192 + head * 24;  // z_sw: K=6144
    chB[q] = (head * 48 + n_t * 8 + wn * 4 + q) * 24;   // w1t_sw: K=768
  }
  floatx4 acc[4][4];
#pragma unroll
  for (int i = 0; i < 4; ++i)
#pragma unroll
    for (int j = 0; j < 4; ++j) acc[i][j] = {0.f, 0.f, 0.f, 0.f};

  GEMM_PTRS(Asw, Bsw)
  GEMM_KLOOP(24)

  // epilogue: bias+ELU -> LDS tile -> fragment-tiled global write
  const float* bias = biasb + head * 768 + n_t * 128;
#pragma unroll
  for (int i = 0; i < 4; ++i) {
    int row_l = wm * 64 + i * 16 + lq * 4;
#pragma unroll
    for (int j = 0; j < 4; ++j) {
      int col_l = wn * 64 + j * 16 + lrow;
      float bv = bias[col_l];
#pragma unroll
      for (int r = 0; r < 4; ++r) {
        float v = acc[i][j][r] + bv;
        v = v > 0.f ? v : expm1f(v);  // ELU
        tile[(row_l + r) * 136 + col_l] = f2bf(v);
      }
    }
  }
  __syncthreads();
#pragma unroll
  for (int cc = 0; cc < 8; ++cc) {
    int ch = w * 8 + cc;          // 32 chunks in the 128x128 tile
    int RB = ch >> 2, kg = ch & 3;
    short8 vv = *(const short8*)&tile[(RB * 16 + lrow) * 136 + kg * 32 + lq * 8];
    size_t chunk_g = (size_t)(m_t * 8 + RB) * 192 + head * 24 + n_t * 4 + kg;
    *((short8*)Csw + chunk_g * 64 + lane) = vv;
  }
}

// ---------------------------------------------------------------------------
// Layer-2 GEMM split-K=4 (128x128 tile, LDS-free): partials fp32 row-major.
// Grid 1536: c=id&7: s=c>>1 (K-slice per XCD-pair), m_t=(j/6)*2+(c&1), n_t=j%6.
// ---------------------------------------------------------------------------
__global__ __launch_bounds__(256) void gemm_l2_kernel(
    const ushort_t* __restrict__ Asw, const ushort_t* __restrict__ Bsw,
    float* __restrict__ Cp) {
  const int id = blockIdx.x;
  const int c = id & 7;
  const int s = c >> 1;
  const int j_id = id >> 3;
  const int n_t = j_id % 6;
  const int m_t = (j_id / 6) * 2 + (c & 1);
  const int tid = threadIdx.x;
  const int lane = tid & 63;
  const int w = tid >> 6;
  const int wm = w >> 1, wn = w & 1;
  const int lrow = lane & 15, lq = lane >> 4;

  int chA[4], chB[4];
#pragma unroll
  for (int q = 0; q < 4; ++q) {
    chA[q] = (m_t * 8 + wm * 4 + q) * 192 + s * 48;  // h2b_sw: K=6144
    chB[q] = (n_t * 8 + wn * 4 + q) * 192 + s * 48;  // w2t_sw: K=6144
  }
  floatx4 acc[4][4];
#pragma unroll
  for (int i = 0; i < 4; ++i)
#pragma unroll
    for (int j = 0; j < 4; ++j) acc[i][j] = {0.f, 0.f, 0.f, 0.f};

  GEMM_PTRS(Asw, Bsw)
  GEMM_KLOOP(48)

  float* C = Cp + (size_t)s * N_NODES * 768;
  const int m0 = m_t * 128, n0 = n_t * 128;
#pragma unroll
  for (int i = 0; i < 4; ++i) {
    int row_b = m0 + wm * 64 + i * 16 + lq * 4;
#pragma unroll
    for (int j = 0; j < 4; ++j) {
      int col = n0 + wn * 64 + j * 16 + lrow;
#pragma unroll
      for (int r = 0; r < 4; ++r)
        C[(size_t)(row_b + r) * 768 + col] = acc[i][j][r];
    }
  }
}

// ---------------------------------------------------------------------------
// Fused: yb = bf16(sum of 4 partials); as2/ad2 = y . a_src2/a_dst2 per node.
// ---------------------------------------------------------------------------
__global__ void reduce_alpha2_kernel(const float* __restrict__ parts,
                                     const float* __restrict__ aS,
                                     const float* __restrict__ aD,
                                     ushort_t* __restrict__ yb,
                                     float* __restrict__ as2,
                                     float* __restrict__ ad2) {
  const int n = blockIdx.x;
  const int t = threadIdx.x;
  const size_t S = (size_t)N_NODES * 768;
  float ps = 0.f, pd = 0.f;
#pragma unroll
  for (int j = 0; j < 3; ++j) {
    int cidx = j * 256 + t;
    size_t base = (size_t)n * 768 + cidx;
    float v = parts[base] + parts[base + S] + parts[base + 2 * S] +
              parts[base + 3 * S];
    yb[base] = f2bf(v);
    ps += v * aS[cidx];
    pd += v * aD[cidx];
  }
  for (int off = 32; off > 0; off >>= 1) {
    ps += __shfl_down(ps, off, 64);
    pd += __shfl_down(pd, off, 64);
  }
  __shared__ float red[2][4];
  int w = t >> 6;
  if ((t & 63) == 0) { red[0][w] = ps; red[1][w] = pd; }
  __syncthreads();
  if (t == 0) as2[n] = red[0][0] + red[0][1] + red[0][2] + red[0][3];
  if (t == 64) ad2[n] = red[1][0] + red[1][1] + red[1][2] + red[1][3];
}

// ---------------------------------------------------------------------------
// Fused layer-2 attention (H=1) + bias: out[n,c] = sum alpha*y[src,c] + b2.
// ---------------------------------------------------------------------------
__global__ __launch_bounds__(256) void attn2_kernel(
    const ushort_t* __restrict__ yb, const float* __restrict__ as2,
    const float* __restrict__ ad2, const int* __restrict__ start,
    const int* __restrict__ deg, const int* __restrict__ csr,
    const int* __restrict__ src, const float* __restrict__ b2,
    float* __restrict__ out) {
  const int n = blockIdx.x;
  const int t = threadIdx.x;
  const int st = start[n], dg = deg[n];
  __shared__ float alphaS[64];
  __shared__ int sidx[64];
  __shared__ float red[4];
  __shared__ float invd_sh;

  const float adv = ad2[n];
  float pden = 0.f;
  for (int ei = t; ei < dg; ei += 256) {
    int e = csr[st + ei];
    int s = (e < N_EDGES) ? src[e] : (e - N_EDGES);
    float l = as2[s] + adv;
    l = l > 0.f ? l : 0.2f * l;
    pden += __expf(l);
  }
  for (int off = 32; off > 0; off >>= 1) pden += __shfl_down(pden, off, 64);
  if ((t & 63) == 0) red[t >> 6] = pden;
  __syncthreads();
  if (t == 0) invd_sh = 1.0f / (red[0] + red[1] + red[2] + red[3]);
  __syncthreads();
  const float invd = invd_sh;

  float a0 = 0.f, a1 = 0.f, a2 = 0.f;
  for (int base = 0; base < dg; base += 64) {
    int cnt = dg - base; if (cnt > 64) cnt = 64;
    if (t < cnt) {
      int e = csr[st + base + t];
      int s = (e < N_EDGES) ? src[e] : (e - N_EDGES);
      float l = as2[s] + adv;
      l = l > 0.f ? l : 0.2f * l;
      alphaS[t] = __expf(l) * invd;
      sidx[t] = s;
    }
    __syncthreads();
    for (int ei = 0; ei < cnt; ++ei) {
      float al = alphaS[ei];
      const ushort_t* row = yb + (size_t)sidx[ei] * 768;
      a0 += al * bf2f(row[t]);
      a1 += al * bf2f(row[t + 256]);
      a2 += al * bf2f(row[t + 512]);
    }
    __syncthreads();
  }
  out[(size_t)n * 768 + t]       = a0 + b2[t];
  out[(size_t)n * 768 + t + 256] = a1 + b2[t + 256];
  out[(size_t)n * 768 + t + 512] = a2 + b2[t + 512];
}

// ---------------------------------------------------------------------------
extern "C" void kernel_launch(void* const* d_in, const int* in_sizes, int n_in,
                              void* d_out, int out_size, void* d_ws, size_t ws_size,
                              hipStream_t stream) {
  const float* x      = (const float*)d_in[0];
  const int*   ei     = (const int*)d_in[1];
  const float* W1     = (const float*)d_in[2];
  const float* a_src1 = (const float*)d_in[3];
  const float* a_dst1 = (const float*)d_in[4];
  const float* b1     = (const float*)d_in[5];
  const float* W2     = (const float*)d_in[6];
  const float* a_src2 = (const float*)d_in[7];
  const float* a_dst2 = (const float*)d_in[8];
  const float* b2     = (const float*)d_in[9];
  float* out = (float*)d_out;
  const int* src = ei;
  const int* dst = ei + N_EDGES;

  char* ws = (char*)d_ws;
  size_t off = 0;
  auto alloc = [&](size_t bytes) -> void* {
    void* p = ws + off;
    off = (off + bytes + 255) & ~(size_t)255;
    return p;
  };

  int* deg = (int*)alloc(N_NODES * 4);  // needs zero-init
  float* awS = (float*)alloc(768 * H1 * 4);
  float* awD = (float*)alloc(768 * H1 * 4);
  float* as1 = (float*)alloc(N_NODES * H1 * 4);
  float* ad1 = (float*)alloc(N_NODES * H1 * 4);
  float* as2 = (float*)alloc(N_NODES * 4);
  float* ad2 = (float*)alloc(N_NODES * 4);
  int* start  = (int*)alloc(N_NODES * 4);
  int* cursor = (int*)alloc(N_NODES * 4);
  int* csr    = (int*)alloc(E_TOT * 4);
  // +8192-byte pads: GEMM K-loop tail over-reads <=2 chunks (4 KB) per stream
  ushort_t* xb     = (ushort_t*)alloc((size_t)N_NODES * D_IN * 2);  // -> yb
  ushort_t* w1t_sw = (ushort_t*)alloc((size_t)HC1 * D_IN * 2 + 8192);
  ushort_t* w2t_sw = (ushort_t*)alloc((size_t)HC1 * D_IN * 2 + 8192);
  ushort_t* z_sw   = (ushort_t*)alloc((size_t)N_NODES * HC1 * 2 + 8192);
  ushort_t* h2b_sw = (ushort_t*)alloc((size_t)N_NODES * HC1 * 2 + 8192);
  ushort_t* yb  = xb;            // xb dead after attn1
  float* parts  = (float*)z_sw;  // z dead after gemm_l1 (96 MB <= 100.7 MB)
  (void)ws_size; (void)n_in; (void)in_sizes; (void)out_size;

  hipMemsetAsync(deg, 0, N_NODES * 4, stream);

  // weight prep
  prep_aw_kernel<<<768, 256, 0, stream>>>(W1, a_src1, a_dst1, awS, awD);
  node_prep_kernel<<<N_NODES, 256, 0, stream>>>(x, awS, awD, xb, as1, ad1);
  // w1t_sw = sw(Bt of W1): Bt[6144][768]
  frag_transpose_kernel<<<dim3(HC1 / 16, D_IN / 32), 64, 0, stream>>>(
      W1, w1t_sw, D_IN, HC1);
  // w2t_sw = sw(Bt of W2): Bt[768][6144]
  frag_transpose_kernel<<<dim3(D_IN / 16, HC1 / 32), 64, 0, stream>>>(
      W2, w2t_sw, HC1, D_IN);

  // CSR build (graph identical for both layers)
  deg_kernel<<<(E_TOT + 255) / 256, 256, 0, stream>>>(dst, deg);
  scan_kernel<<<1, 1024, 0, stream>>>(deg, start, cursor);
  fill_kernel<<<(E_TOT + 255) / 256, 256, 0, stream>>>(dst, cursor, csr);

  // layer-1: fused attention -> z_sw, then per-head LDS-free GEMM
  attn1_kernel<<<N_NODES, 256, 0, stream>>>(xb, as1, ad1, start, deg, csr,
                                            src, z_sw);
  gemm_l1_kernel<<<8 * 64 * 6, 256, 0, stream>>>(z_sw, w1t_sw, b1, h2b_sw);

  // layer-2: split-K LDS-free GEMM -> fused reduce+alpha -> attention + bias
  gemm_l2_kernel<<<KSPLIT * 2 * 32 * 6, 256, 0, stream>>>(h2b_sw, w2t_sw,
                                                          parts);
  reduce_alpha2_kernel<<<N_NODES, 256, 0, stream>>>(parts, a_src2, a_dst2, yb,
                                                    as2, ad2);
  attn2_kernel<<<N_NODES, 256, 0, stream>>>(yb, as2, ad2, start, deg, csr,
                                            src, b2, out);
}

// Round 8
// 505.321 us; speedup vs baseline: 1.1946x; 1.0655x over previous
//
#include <hip/hip_runtime.h>
#include <hip/hip_bf16.h>

// ---------------------------------------------------------------------------
// GAT 2-layer model on MI355X — round 8.
// GEMMs are LDS-free: operands pre-swizzled into MFMA-fragment-tiled layout
// (1 KB chunk = one 16x32 bf16 fragment; lane L owns bytes L*16..+16).
// K-loop: R5's 2-chunk prefetch distance, runtime-k loop, with chunk indices
// forced wave-uniform via readfirstlane -> saddr-form loads (SGPR base +
// shared lane offset + imm), ~30 fewer VGPRs -> 3 waves/SIMD (was 2).
// Epilogue ELU via __expf-1 (R7 post-mortem: expm1f libm call was ~1/3 of
// VALUBusy in gemm_l1).
// Layer1 commuted: z = softmax-agg of x rows (attn1 writes z_sw directly)
//                  h2 = ELU(z_h @ W1_h + b1)  (epilogue LDS-transposes tile
//                  to write h2b_sw fragment-tiled)
// Layer2: y = h2@W2 split-K=4 -> fused reduce+alpha -> attn2+b2.
// ---------------------------------------------------------------------------

#define N_NODES 8192
#define N_EDGES 32768
#define E_TOT   (N_EDGES + N_NODES)   // self-loops appended
#define D_IN    768
#define H1      8
#define HC1     (H1 * D_IN)           // 6144
#define KSPLIT  4
#define KSLICE  (HC1 / KSPLIT)        // 1536

typedef unsigned short ushort_t;
using short8  = __attribute__((ext_vector_type(8))) short;
using floatx4 = __attribute__((ext_vector_type(4))) float;

__device__ __forceinline__ float bf2f(unsigned short u) {
  return __uint_as_float(((unsigned)u) << 16);
}
__device__ __forceinline__ unsigned short f2bf(float f) {
  unsigned u = __float_as_uint(f);
  unsigned r = (u + 0x7fffu + ((u >> 16) & 1u)) >> 16;  // RNE
  return (unsigned short)r;
}

// ---------------------------------------------------------------------------
// frag_transpose: W[Kdim][Ndim] fp32 row-major -> sw-layout of Bt[N][K] bf16.
// ---------------------------------------------------------------------------
__global__ __launch_bounds__(64) void frag_transpose_kernel(
    const float* __restrict__ W, ushort_t* __restrict__ out,
    int Kdim, int Ndim) {
  const int bn = blockIdx.x;
  const int bk = blockIdx.y;
  const int lane = threadIdx.x;
  const int lrow = lane & 15, lq = lane >> 4;
  const int n = bn * 16 + lrow;
  const int kb = bk * 32 + lq * 8;
  ushort_t v[8];
#pragma unroll
  for (int e = 0; e < 8; ++e)
    v[e] = f2bf(W[(size_t)(kb + e) * Ndim + n]);
  *(short8*)(out + ((size_t)bn * (Kdim >> 5) + bk) * 512 + lane * 8) =
      *(short8*)v;
}

// ---------------------------------------------------------------------------
// awS[d][h] = sum_c W1[d][h*768+c]*a_src1[h*768+c]; awD likewise.
// ---------------------------------------------------------------------------
__global__ void prep_aw_kernel(const float* __restrict__ W1,
                               const float* __restrict__ aS,
                               const float* __restrict__ aD,
                               float* __restrict__ awS,
                               float* __restrict__ awD) {
  const int d = blockIdx.x;
  const int t = threadIdx.x;
  const float* row = W1 + (size_t)d * HC1;
  float ps[H1], pd[H1];
#pragma unroll
  for (int h = 0; h < H1; ++h) { ps[h] = 0.f; pd[h] = 0.f; }
#pragma unroll
  for (int h = 0; h < H1; ++h)
#pragma unroll
    for (int j = 0; j < 3; ++j) {
      int idx = h * 768 + j * 256 + t;
      float w = row[idx];
      ps[h] += w * aS[idx];
      pd[h] += w * aD[idx];
    }
#pragma unroll
  for (int h = 0; h < H1; ++h)
    for (int off = 32; off > 0; off >>= 1) {
      ps[h] += __shfl_down(ps[h], off, 64);
      pd[h] += __shfl_down(pd[h], off, 64);
    }
  __shared__ float red[2][4][H1];
  int w = t >> 6;
  if ((t & 63) == 0) {
#pragma unroll
    for (int h = 0; h < H1; ++h) { red[0][w][h] = ps[h]; red[1][w][h] = pd[h]; }
  }
  __syncthreads();
  if (t < H1)
    awS[d * H1 + t] = red[0][0][t] + red[0][1][t] + red[0][2][t] + red[0][3][t];
  else if (t >= 64 && t < 64 + H1) {
    int h = t - 64;
    awD[d * H1 + h] = red[1][0][h] + red[1][1][h] + red[1][2][h] + red[1][3][h];
  }
}

// ---------------------------------------------------------------------------
// per node: xb = bf16(x); as1[n,h] = x[n,:]@awS[:,h]; ad1 likewise.
// ---------------------------------------------------------------------------
__global__ void node_prep_kernel(const float* __restrict__ x,
                                 const float* __restrict__ awS,
                                 const float* __restrict__ awD,
                                 ushort_t* __restrict__ xb,
                                 float* __restrict__ as1,
                                 float* __restrict__ ad1) {
  const int n = blockIdx.x;
  const int t = threadIdx.x;
  float ps[H1], pd[H1];
#pragma unroll
  for (int h = 0; h < H1; ++h) { ps[h] = 0.f; pd[h] = 0.f; }
#pragma unroll
  for (int j = 0; j < 3; ++j) {
    int d = j * 256 + t;
    float xv = x[(size_t)n * 768 + d];
    xb[(size_t)n * 768 + d] = f2bf(xv);
    const float4* s4 = (const float4*)(awS + d * 8);
    const float4* d4 = (const float4*)(awD + d * 8);
    float4 a0 = s4[0], a1 = s4[1];
    float4 c0 = d4[0], c1 = d4[1];
    ps[0] += xv * a0.x; ps[1] += xv * a0.y; ps[2] += xv * a0.z; ps[3] += xv * a0.w;
    ps[4] += xv * a1.x; ps[5] += xv * a1.y; ps[6] += xv * a1.z; ps[7] += xv * a1.w;
    pd[0] += xv * c0.x; pd[1] += xv * c0.y; pd[2] += xv * c0.z; pd[3] += xv * c0.w;
    pd[4] += xv * c1.x; pd[5] += xv * c1.y; pd[6] += xv * c1.z; pd[7] += xv * c1.w;
  }
#pragma unroll
  for (int h = 0; h < H1; ++h)
    for (int off = 32; off > 0; off >>= 1) {
      ps[h] += __shfl_down(ps[h], off, 64);
      pd[h] += __shfl_down(pd[h], off, 64);
    }
  __shared__ float red[2][4][H1];
  int w = t >> 6;
  if ((t & 63) == 0) {
#pragma unroll
    for (int h = 0; h < H1; ++h) { red[0][w][h] = ps[h]; red[1][w][h] = pd[h]; }
  }
  __syncthreads();
  if (t < H1)
    as1[n * H1 + t] = red[0][0][t] + red[0][1][t] + red[0][2][t] + red[0][3][t];
  else if (t >= 64 && t < 64 + H1) {
    int h = t - 64;
    ad1[n * H1 + h] = red[1][0][h] + red[1][1][h] + red[1][2][h] + red[1][3][h];
  }
}

// ---------------------------------------------------------------------------
// CSR build: deg -> exclusive scan -> fill
// ---------------------------------------------------------------------------
__global__ void deg_kernel(const int* __restrict__ dst, int* __restrict__ deg) {
  int e = blockIdx.x * blockDim.x + threadIdx.x;
  if (e >= E_TOT) return;
  int d = (e < N_EDGES) ? dst[e] : (e - N_EDGES);
  atomicAdd(&deg[d], 1);
}

__global__ void scan_kernel(const int* __restrict__ deg, int* __restrict__ start,
                            int* __restrict__ cursor) {
  __shared__ int sums[1024];
  int t = threadIdx.x;
  int base = t * 8;
  int local[8];
  int s = 0;
#pragma unroll
  for (int i = 0; i < 8; ++i) { local[i] = s; s += deg[base + i]; }
  sums[t] = s;
  __syncthreads();
  for (int off = 1; off < 1024; off <<= 1) {
    int v = (t >= off) ? sums[t - off] : 0;
    __syncthreads();
    sums[t] += v;
    __syncthreads();
  }
  int excl = (t == 0) ? 0 : sums[t - 1];
#pragma unroll
  for (int i = 0; i < 8; ++i) {
    int st = excl + local[i];
    start[base + i] = st;
    cursor[base + i] = st;
  }
}

__global__ void fill_kernel(const int* __restrict__ dst, int* __restrict__ cursor,
                            int* __restrict__ csr) {
  int e = blockIdx.x * blockDim.x + threadIdx.x;
  if (e >= E_TOT) return;
  int d = (e < N_EDGES) ? dst[e] : (e - N_EDGES);
  int pos = atomicAdd(&cursor[d], 1);
  csr[pos] = e;
}

// ---------------------------------------------------------------------------
// Fused layer-1 attention -> z in sw (fragment-tiled) layout.
// ---------------------------------------------------------------------------
__global__ __launch_bounds__(256) void attn1_kernel(
    const ushort_t* __restrict__ xb, const float* __restrict__ as1,
    const float* __restrict__ ad1, const int* __restrict__ start,
    const int* __restrict__ deg, const int* __restrict__ csr,
    const int* __restrict__ src, ushort_t* __restrict__ z_sw) {
  const int n = blockIdx.x;
  const int t = threadIdx.x;
  const int st = start[n], dg = deg[n];
  const int h = t & 7, eloc = t >> 3;  // 32 edges x 8 heads per chunk
  __shared__ float invd[H1];
  __shared__ float alphaS[32][H1];
  __shared__ int sidx[32];
  __shared__ float red[4][H1];

  // Phase A: denominators (no max-subtraction; logits bounded)
  const float adv = ad1[n * H1 + h];
  float pden = 0.f;
  for (int base = 0; base < dg; base += 32) {
    int ei = base + eloc;
    if (ei < dg) {
      int e = csr[st + ei];
      int s = (e < N_EDGES) ? src[e] : (e - N_EDGES);
      float l = as1[s * H1 + h] + adv;
      l = l > 0.f ? l : 0.2f * l;
      pden += __expf(l);
    }
  }
  pden += __shfl_down(pden, 8, 64);
  pden += __shfl_down(pden, 16, 64);
  pden += __shfl_down(pden, 32, 64);
  if ((t & 63) < 8) red[t >> 6][h] = pden;
  __syncthreads();
  if (t < 8) invd[t] = 1.0f / (red[0][t] + red[1][t] + red[2][t] + red[3][t]);
  __syncthreads();

  // per-pass ownership
  int hp[3], ip[3];
#pragma unroll
  for (int p = 0; p < 3; ++p) {
    int c8 = p * 256 + t;
    hp[p] = c8 / 96;          // head
    ip[p] = c8 % 96;          // uint4 index within xb row
  }
  float acc[3][8];
#pragma unroll
  for (int p = 0; p < 3; ++p)
#pragma unroll
    for (int e = 0; e < 8; ++e) acc[p][e] = 0.f;

  for (int base = 0; base < dg; base += 32) {
    int cnt = dg - base; if (cnt > 32) cnt = 32;
    if (eloc < cnt) {
      int e = csr[st + base + eloc];
      int s = (e < N_EDGES) ? src[e] : (e - N_EDGES);
      float l = as1[s * H1 + h] + adv;
      l = l > 0.f ? l : 0.2f * l;
      alphaS[eloc][h] = __expf(l) * invd[h];
      if (h == 0) sidx[eloc] = s;
    }
    __syncthreads();
    for (int ei = 0; ei < cnt; ++ei) {
      int s = sidx[ei];
      const uint4* xrow = (const uint4*)(xb + (size_t)s * 768);
#pragma unroll
      for (int p = 0; p < 3; ++p) {
        uint4 v = xrow[ip[p]];
        float al = alphaS[ei][hp[p]];
        unsigned uu[4] = {v.x, v.y, v.z, v.w};
#pragma unroll
        for (int q = 0; q < 4; ++q) {
          acc[p][2 * q]     += al * __uint_as_float(uu[q] << 16);
          acc[p][2 * q + 1] += al * __uint_as_float(uu[q] & 0xffff0000u);
        }
      }
    }
    __syncthreads();
  }
  // write sw layout: k = (p*256+t)*8
#pragma unroll
  for (int p = 0; p < 3; ++p) {
    int c8 = p * 256 + t;
    int k = c8 * 8;
    size_t chunk = (size_t)(n >> 4) * 192 + (k >> 5);
    int word = ((k >> 3) & 3) * 16 + (n & 15);
    ushort_t v[8];
#pragma unroll
    for (int e = 0; e < 8; ++e) v[e] = f2bf(acc[p][e]);
    *(short8*)(z_sw + chunk * 512 + word * 8) = *(short8*)v;
  }
}

// ---------------------------------------------------------------------------
// LDS-free MFMA helpers. Chunk indices are wave-uniform (readfirstlane-forced
// SGPRs) -> saddr-form loads; R5's 2-chunk prefetch distance; unconditional
// tail over-read <=3 chunks (workspace padded 8 KB).
// ---------------------------------------------------------------------------
#define LOADI(dst, BASE, CH, kk)                                               \
  _Pragma("unroll") for (int q = 0; q < 4; ++q)                                \
      dst[q] = *(const short8*)((BASE) +                                       \
                                (((size_t)((CH)[q] + (kk))) << 9) + lane8);

#define MFMA16(af, bf)                                                         \
  _Pragma("unroll") for (int i_ = 0; i_ < 4; ++i_)                             \
      _Pragma("unroll") for (int j_ = 0; j_ < 4; ++j_)                         \
          acc[i_][j_] = __builtin_amdgcn_mfma_f32_16x16x32_bf16(               \
              af[i_], bf[j_], acc[i_][j_], 0, 0, 0);

#define GEMM_KLOOP(NCH, ABASE, BBASE)                                          \
  {                                                                            \
    short8 a0[4], b0[4], a1[4], b1[4];                                         \
    LOADI(a0, ABASE, chA, 0) LOADI(b0, BBASE, chB, 0)                          \
    LOADI(a1, ABASE, chA, 1) LOADI(b1, BBASE, chB, 1)                          \
    for (int k = 0; k < (NCH); k += 2) {                                       \
      MFMA16(a0, b0)                                                           \
      LOADI(a0, ABASE, chA, k + 2) LOADI(b0, BBASE, chB, k + 2)                \
      MFMA16(a1, b1)                                                           \
      LOADI(a1, ABASE, chA, k + 3) LOADI(b1, BBASE, chB, k + 3)                \
    }                                                                          \
  }

// ---------------------------------------------------------------------------
// Layer-1 GEMM (per-head, 128x128 tile, LDS-free): h2 = ELU(z_h@W1_h^T + b1).
// Grid 3072: head = id&7 (pins head per XCD), j=id>>3: n_t=j%6, m_t=j/6.
// Epilogue: LDS-transpose the C tile and store h2b in sw layout (K=6144).
// ---------------------------------------------------------------------------
__global__ __launch_bounds__(256) void gemm_l1_kernel(
    const ushort_t* __restrict__ Asw, const ushort_t* __restrict__ Bsw,
    const float* __restrict__ biasb, ushort_t* __restrict__ Csw) {
  __shared__ ushort_t tile[128 * 136];
  const int id = blockIdx.x;
  const int head = id & 7;
  const int j_id = id >> 3;
  const int n_t = j_id % 6;
  const int m_t = j_id / 6;
  const int tid = threadIdx.x;
  const int lane = tid & 63;
  const int w = tid >> 6;
  const int wm = w >> 1, wn = w & 1;
  const int lrow = lane & 15, lq = lane >> 4;
  const int lane8 = lane * 8;

  int chA[4], chB[4];
#pragma unroll
  for (int q = 0; q < 4; ++q) {
    chA[q] = __builtin_amdgcn_readfirstlane((m_t * 8 + wm * 4 + q) * 192 +
                                            head * 24);          // z_sw K=6144
    chB[q] = __builtin_amdgcn_readfirstlane((head * 48 + n_t * 8 + wn * 4 + q) *
                                            24);                 // w1t K=768
  }
  floatx4 acc[4][4];
#pragma unroll
  for (int i = 0; i < 4; ++i)
#pragma unroll
    for (int j = 0; j < 4; ++j) acc[i][j] = {0.f, 0.f, 0.f, 0.f};

  GEMM_KLOOP(24, Asw, Bsw)

  // epilogue: bias+ELU -> LDS tile -> fragment-tiled global write
  const float* bias = biasb + head * 768 + n_t * 128;
#pragma unroll
  for (int i = 0; i < 4; ++i) {
    int row_l = wm * 64 + i * 16 + lq * 4;
#pragma unroll
    for (int j = 0; j < 4; ++j) {
      int col_l = wn * 64 + j * 16 + lrow;
      float bv = bias[col_l];
#pragma unroll
      for (int r = 0; r < 4; ++r) {
        float v = acc[i][j][r] + bv;
        v = v > 0.f ? v : __expf(v) - 1.0f;  // ELU (fast exp)
        tile[(row_l + r) * 136 + col_l] = f2bf(v);
      }
    }
  }
  __syncthreads();
#pragma unroll
  for (int cc = 0; cc < 8; ++cc) {
    int ch = w * 8 + cc;          // 32 chunks in the 128x128 tile
    int RB = ch >> 2, kg = ch & 3;
    short8 vv = *(const short8*)&tile[(RB * 16 + lrow) * 136 + kg * 32 + lq * 8];
    size_t chunk_g = (size_t)(m_t * 8 + RB) * 192 + head * 24 + n_t * 4 + kg;
    *((short8*)Csw + chunk_g * 64 + lane) = vv;
  }
}

// ---------------------------------------------------------------------------
// Layer-2 GEMM split-K=4 (128x128 tile, LDS-free): partials fp32 row-major.
// Grid 1536: c=id&7: s=c>>1 (K-slice per XCD-pair), m_t=(j/6)*2+(c&1), n_t=j%6.
// ---------------------------------------------------------------------------
__global__ __launch_bounds__(256) void gemm_l2_kernel(
    const ushort_t* __restrict__ Asw, const ushort_t* __restrict__ Bsw,
    float* __restrict__ Cp) {
  const int id = blockIdx.x;
  const int c = id & 7;
  const int s = c >> 1;
  const int j_id = id >> 3;
  const int n_t = j_id % 6;
  const int m_t = (j_id / 6) * 2 + (c & 1);
  const int tid = threadIdx.x;
  const int lane = tid & 63;
  const int w = tid >> 6;
  const int wm = w >> 1, wn = w & 1;
  const int lrow = lane & 15, lq = lane >> 4;
  const int lane8 = lane * 8;

  int chA[4], chB[4];
#pragma unroll
  for (int q = 0; q < 4; ++q) {
    chA[q] = __builtin_amdgcn_readfirstlane((m_t * 8 + wm * 4 + q) * 192 +
                                            s * 48);  // h2b_sw K=6144
    chB[q] = __builtin_amdgcn_readfirstlane((n_t * 8 + wn * 4 + q) * 192 +
                                            s * 48);  // w2t_sw K=6144
  }
  floatx4 acc[4][4];
#pragma unroll
  for (int i = 0; i < 4; ++i)
#pragma unroll
    for (int j = 0; j < 4; ++j) acc[i][j] = {0.f, 0.f, 0.f, 0.f};

  GEMM_KLOOP(48, Asw, Bsw)

  float* C = Cp + (size_t)s * N_NODES * 768;
  const int m0 = m_t * 128, n0 = n_t * 128;
#pragma unroll
  for (int i = 0; i < 4; ++i) {
    int row_b = m0 + wm * 64 + i * 16 + lq * 4;
#pragma unroll
    for (int j = 0; j < 4; ++j) {
      int col = n0 + wn * 64 + j * 16 + lrow;
#pragma unroll
      for (int r = 0; r < 4; ++r)
        C[(size_t)(row_b + r) * 768 + col] = acc[i][j][r];
    }
  }
}

// ---------------------------------------------------------------------------
// Fused: yb = bf16(sum of 4 partials); as2/ad2 = y . a_src2/a_dst2 per node.
// ---------------------------------------------------------------------------
__global__ void reduce_alpha2_kernel(const float* __restrict__ parts,
                                     const float* __restrict__ aS,
                                     const float* __restrict__ aD,
                                     ushort_t* __restrict__ yb,
                                     float* __restrict__ as2,
                                     float* __restrict__ ad2) {
  const int n = blockIdx.x;
  const int t = threadIdx.x;
  const size_t S = (size_t)N_NODES * 768;
  float ps = 0.f, pd = 0.f;
#pragma unroll
  for (int j = 0; j < 3; ++j) {
    int cidx = j * 256 + t;
    size_t base = (size_t)n * 768 + cidx;
    float v = parts[base] + parts[base + S] + parts[base + 2 * S] +
              parts[base + 3 * S];
    yb[base] = f2bf(v);
    ps += v * aS[cidx];
    pd += v * aD[cidx];
  }
  for (int off = 32; off > 0; off >>= 1) {
    ps += __shfl_down(ps, off, 64);
    pd += __shfl_down(pd, off, 64);
  }
  __shared__ float red[2][4];
  int w = t >> 6;
  if ((t & 63) == 0) { red[0][w] = ps; red[1][w] = pd; }
  __syncthreads();
  if (t == 0) as2[n] = red[0][0] + red[0][1] + red[0][2] + red[0][3];
  if (t == 64) ad2[n] = red[1][0] + red[1][1] + red[1][2] + red[1][3];
}

// ---------------------------------------------------------------------------
// Fused layer-2 attention (H=1) + bias: out[n,c] = sum alpha*y[src,c] + b2.
// ---------------------------------------------------------------------------
__global__ __launch_bounds__(256) void attn2_kernel(
    const ushort_t* __restrict__ yb, const float* __restrict__ as2,
    const float* __restrict__ ad2, const int* __restrict__ start,
    const int* __restrict__ deg, const int* __restrict__ csr,
    const int* __restrict__ src, const float* __restrict__ b2,
    float* __restrict__ out) {
  const int n = blockIdx.x;
  const int t = threadIdx.x;
  const int st = start[n], dg = deg[n];
  __shared__ float alphaS[64];
  __shared__ int sidx[64];
  __shared__ float red[4];
  __shared__ float invd_sh;

  const float adv = ad2[n];
  float pden = 0.f;
  for (int ei = t; ei < dg; ei += 256) {
    int e = csr[st + ei];
    int s = (e < N_EDGES) ? src[e] : (e - N_EDGES);
    float l = as2[s] + adv;
    l = l > 0.f ? l : 0.2f * l;
    pden += __expf(l);
  }
  for (int off = 32; off > 0; off >>= 1) pden += __shfl_down(pden, off, 64);
  if ((t & 63) == 0) red[t >> 6] = pden;
  __syncthreads();
  if (t == 0) invd_sh = 1.0f / (red[0] + red[1] + red[2] + red[3]);
  __syncthreads();
  const float invd = invd_sh;

  float a0 = 0.f, a1 = 0.f, a2 = 0.f;
  for (int base = 0; base < dg; base += 64) {
    int cnt = dg - base; if (cnt > 64) cnt = 64;
    if (t < cnt) {
      int e = csr[st + base + t];
      int s = (e < N_EDGES) ? src[e] : (e - N_EDGES);
      float l = as2[s] + adv;
      l = l > 0.f ? l : 0.2f * l;
      alphaS[t] = __expf(l) * invd;
      sidx[t] = s;
    }
    __syncthreads();
    for (int ei = 0; ei < cnt; ++ei) {
      float al = alphaS[ei];
      const ushort_t* row = yb + (size_t)sidx[ei] * 768;
      a0 += al * bf2f(row[t]);
      a1 += al * bf2f(row[t + 256]);
      a2 += al * bf2f(row[t + 512]);
    }
    __syncthreads();
  }
  out[(size_t)n * 768 + t]       = a0 + b2[t];
  out[(size_t)n * 768 + t + 256] = a1 + b2[t + 256];
  out[(size_t)n * 768 + t + 512] = a2 + b2[t + 512];
}

// ---------------------------------------------------------------------------
extern "C" void kernel_launch(void* const* d_in, const int* in_sizes, int n_in,
                              void* d_out, int out_size, void* d_ws, size_t ws_size,
                              hipStream_t stream) {
  const float* x      = (const float*)d_in[0];
  const int*   ei     = (const int*)d_in[1];
  const float* W1     = (const float*)d_in[2];
  const float* a_src1 = (const float*)d_in[3];
  const float* a_dst1 = (const float*)d_in[4];
  const float* b1     = (const float*)d_in[5];
  const float* W2     = (const float*)d_in[6];
  const float* a_src2 = (const float*)d_in[7];
  const float* a_dst2 = (const float*)d_in[8];
  const float* b2     = (const float*)d_in[9];
  float* out = (float*)d_out;
  const int* src = ei;
  const int* dst = ei + N_EDGES;

  char* ws = (char*)d_ws;
  size_t off = 0;
  auto alloc = [&](size_t bytes) -> void* {
    void* p = ws + off;
    off = (off + bytes + 255) & ~(size_t)255;
    return p;
  };

  int* deg = (int*)alloc(N_NODES * 4);  // needs zero-init
  float* awS = (float*)alloc(768 * H1 * 4);
  float* awD = (float*)alloc(768 * H1 * 4);
  float* as1 = (float*)alloc(N_NODES * H1 * 4);
  float* ad1 = (float*)alloc(N_NODES * H1 * 4);
  float* as2 = (float*)alloc(N_NODES * 4);
  float* ad2 = (float*)alloc(N_NODES * 4);
  int* start  = (int*)alloc(N_NODES * 4);
  int* cursor = (int*)alloc(N_NODES * 4);
  int* csr    = (int*)alloc(E_TOT * 4);
  // +8192-byte pads: GEMM K-loop tail over-reads <=3 chunks per stream
  ushort_t* xb     = (ushort_t*)alloc((size_t)N_NODES * D_IN * 2);  // -> yb
  ushort_t* w1t_sw = (ushort_t*)alloc((size_t)HC1 * D_IN * 2 + 8192);
  ushort_t* w2t_sw = (ushort_t*)alloc((size_t)HC1 * D_IN * 2 + 8192);
  ushort_t* z_sw   = (ushort_t*)alloc((size_t)N_NODES * HC1 * 2 + 8192);
  ushort_t* h2b_sw = (ushort_t*)alloc((size_t)N_NODES * HC1 * 2 + 8192);
  ushort_t* yb  = xb;            // xb dead after attn1
  float* parts  = (float*)z_sw;  // z dead after gemm_l1 (96 MB <= 100.7 MB)
  (void)ws_size; (void)n_in; (void)in_sizes; (void)out_size;

  hipMemsetAsync(deg, 0, N_NODES * 4, stream);

  // weight prep
  prep_aw_kernel<<<768, 256, 0, stream>>>(W1, a_src1, a_dst1, awS, awD);
  node_prep_kernel<<<N_NODES, 256, 0, stream>>>(x, awS, awD, xb, as1, ad1);
  // w1t_sw = sw(Bt of W1): Bt[6144][768]
  frag_transpose_kernel<<<dim3(HC1 / 16, D_IN / 32), 64, 0, stream>>>(
      W1, w1t_sw, D_IN, HC1);
  // w2t_sw = sw(Bt of W2): Bt[768][6144]
  frag_transpose_kernel<<<dim3(D_IN / 16, HC1 / 32), 64, 0, stream>>>(
      W2, w2t_sw, HC1, D_IN);

  // CSR build (graph identical for both layers)
  deg_kernel<<<(E_TOT + 255) / 256, 256, 0, stream>>>(dst, deg);
  scan_kernel<<<1, 1024, 0, stream>>>(deg, start, cursor);
  fill_kernel<<<(E_TOT + 255) / 256, 256, 0, stream>>>(dst, cursor, csr);

  // layer-1: fused attention -> z_sw, then per-head LDS-free GEMM
  attn1_kernel<<<N_NODES, 256, 0, stream>>>(xb, as1, ad1, start, deg, csr,
                                            src, z_sw);
  gemm_l1_kernel<<<8 * 64 * 6, 256, 0, stream>>>(z_sw, w1t_sw, b1, h2b_sw);

  // layer-2: split-K LDS-free GEMM -> fused reduce+alpha -> attention + bias
  gemm_l2_kernel<<<KSPLIT * 2 * 32 * 6, 256, 0, stream>>>(h2b_sw, w2t_sw,
                                                          parts);
  reduce_alpha2_kernel<<<N_NODES, 256, 0, stream>>>(parts, a_src2, a_dst2, yb,
                                                    as2, ad2);
  attn2_kernel<<<N_NODES, 256, 0, stream>>>(yb, as2, ad2, start, deg, csr,
                                            src, b2, out);
}